// Round 14
// baseline (232.748 us; speedup 1.0000x reference)
//
#include <hip/hip_runtime.h>
#include <hip/hip_fp16.h>

#define NN 50000
#define NE 600000
#define LN_EPS 1e-5f
#define SCAN_B 49    // 49 blocks x 1024 nodes covers 50176 >= NN
#define RANGES 8     // node ranges of 6250 (8*6250 = 50000)
#define RSZ 6250
#define CHUNKS 30    // edge chunks of 20000 (30*20000 = 600000); 240 histo blocks
#define CSZ 20000
#define HB (CHUNKS * RANGES)   // 240
#define GB ((NN + 63) / 64)    // 782 gemm tiles
#define G1 390                 // gemm0 tiles overlapped with histo (k1); rest overlap place (k3)

typedef __attribute__((ext_vector_type(8))) _Float16 half8;
typedef __attribute__((ext_vector_type(4))) float floatx4;

// Module-level device scratch (graph-capture safe).
__device__ __align__(16) __half g_h0[NN * 128];
__device__ __align__(16) __half g_h1[NN * 128];
__device__ float g_out_norm[NN];
__device__ float g_in_norm[NN];
__device__ int g_rowptr[NN + 1];
__device__ int g_esrc[NE];
__device__ int g_blocksum[SCAN_B];
__device__ int g_perm[NN];             // degree-sorted node order (kills gather divergence)
__device__ int g_dhist[SCAN_B * 256];  // per-block degree histograms
// CSR-build privatized partials (no device-scope atomics in the hot path)
__device__ int g_pout[CHUNKS * NN];
__device__ int g_pin[CHUNKS * NN];
__device__ int g_base[CHUNKS * NN];
// grid-barrier state for mid_kernel's 49 co-resident blocks (generation-based)
__device__ unsigned g_bar_count = 0;
__device__ unsigned g_bar_gen = 0;

__device__ __forceinline__ __half* hbuf(int i) { return i ? g_h1 : g_h0; }

__device__ __forceinline__ void gridbar(unsigned* expected) {
    __syncthreads();
    if (threadIdx.x == 0) {
        __threadfence();
        unsigned prev = __hip_atomic_fetch_add(&g_bar_count, 1u, __ATOMIC_ACQ_REL,
                                               __HIP_MEMORY_SCOPE_AGENT);
        if (prev == gridDim.x - 1) {
            __hip_atomic_store(&g_bar_count, 0u, __ATOMIC_RELAXED, __HIP_MEMORY_SCOPE_AGENT);
            __hip_atomic_fetch_add(&g_bar_gen, 1u, __ATOMIC_RELEASE, __HIP_MEMORY_SCOPE_AGENT);
        } else {
            while (__hip_atomic_load(&g_bar_gen, __ATOMIC_ACQUIRE, __HIP_MEMORY_SCOPE_AGENT) ==
                   *expected)
                __builtin_amdgcn_s_sleep(8);
        }
        __threadfence();
    }
    __syncthreads();
    (*expected)++;
}

// ---- GEMM0 tile (unscaled): H0[tile rows] = fp16(x @ W0); W staged/swizzled in Wl ----
__device__ __forceinline__ void gemm0_tile(_Float16* Wl, const float* __restrict__ x,
                                           const float* __restrict__ W0, int tile) {
    const int tid = threadIdx.x;
    for (int e = tid; e < 128 * 128; e += 256) {
        int k = e >> 7, n = e & 127;
        Wl[(((k >> 3) * 128 + n) << 3) + (k & 7)] = (_Float16)W0[e];
    }
    __syncthreads();
    const int wv = tid >> 6, lane = tid & 63;
    const int quad = lane >> 4, mrow = lane & 15;
    const int rowbase = tile * 64 + wv * 16;
    const int arow0 = rowbase + mrow;
    const int arow = (arow0 < NN) ? arow0 : (NN - 1);
    floatx4 acc[8] = {};
#pragma unroll
    for (int kk = 0; kk < 4; ++kk) {
        const int k0 = kk * 32 + quad * 8;
        const float4* ap = (const float4*)(x + (size_t)arow * 128 + k0);
        float4 f0 = ap[0], f1 = ap[1];
        half8 afrag;
        afrag[0] = (_Float16)f0.x; afrag[1] = (_Float16)f0.y;
        afrag[2] = (_Float16)f0.z; afrag[3] = (_Float16)f0.w;
        afrag[4] = (_Float16)f1.x; afrag[5] = (_Float16)f1.y;
        afrag[6] = (_Float16)f1.z; afrag[7] = (_Float16)f1.w;
#pragma unroll
        for (int nt = 0; nt < 8; ++nt) {
            half8 bfrag = *(const half8*)&Wl[(((kk * 4 + quad) * 128 + nt * 16 + mrow) << 3)];
            acc[nt] = __builtin_amdgcn_mfma_f32_16x16x32_f16(afrag, bfrag, acc[nt], 0, 0, 0);
        }
    }
    __half* C = hbuf(0);
#pragma unroll
    for (int r = 0; r < 4; ++r) {
        int crow = rowbase + quad * 4 + r;
        if (crow < NN) {
#pragma unroll
            for (int nt = 0; nt < 8; ++nt)
                C[(size_t)crow * 128 + nt * 16 + mrow] = __float2half_rn(acc[nt][r]);
        }
    }
}

// ---- K1: [histo (blocks 0..239)] || [gemm0 tiles 0..G1) ----
__global__ __launch_bounds__(256) void k1_kernel(const int* __restrict__ src,
                                                 const int* __restrict__ dst,
                                                 const float* __restrict__ x,
                                                 const float* __restrict__ W0) {
    __shared__ __align__(16) int s_buf[2 * RSZ];   // 50 KB; union of histo/gemm LDS
    const int tid = threadIdx.x;
    if (blockIdx.x < HB) {
        int* h_out = s_buf;
        int* h_in = s_buf + RSZ;
        int c = blockIdx.x / RANGES, r = blockIdx.x % RANGES;
        int lo = r * RSZ;
        for (int i = tid; i < RSZ; i += 256) { h_out[i] = 0; h_in[i] = 0; }
        __syncthreads();
        const int4* s4 = (const int4*)(src + c * CSZ);
        const int4* d4 = (const int4*)(dst + c * CSZ);
        for (int i = tid; i < CSZ / 4; i += 256) {
            int4 s = s4[i], d = d4[i];
            int v;
            v = s.x - lo; if ((unsigned)v < RSZ) atomicAdd(&h_out[v], 1);
            v = s.y - lo; if ((unsigned)v < RSZ) atomicAdd(&h_out[v], 1);
            v = s.z - lo; if ((unsigned)v < RSZ) atomicAdd(&h_out[v], 1);
            v = s.w - lo; if ((unsigned)v < RSZ) atomicAdd(&h_out[v], 1);
            v = d.x - lo; if ((unsigned)v < RSZ) atomicAdd(&h_in[v], 1);
            v = d.y - lo; if ((unsigned)v < RSZ) atomicAdd(&h_in[v], 1);
            v = d.z - lo; if ((unsigned)v < RSZ) atomicAdd(&h_in[v], 1);
            v = d.w - lo; if ((unsigned)v < RSZ) atomicAdd(&h_in[v], 1);
        }
        __syncthreads();
        for (int i = tid; i < RSZ; i += 256) {
            g_pout[c * NN + lo + i] = h_out[i];
            g_pin[c * NN + lo + i]  = h_in[i];
        }
    } else {
        gemm0_tile((_Float16*)s_buf, x, W0, blockIdx.x - HB);
    }
}

// ---- Fused mid: degrees/norms + exclusive scan (shuffle-based) + cursor bases + degree-sort.
__global__ __launch_bounds__(1024) void mid_kernel() {
    __shared__ int wsum[16], woff[16];
    __shared__ int bscan[64];
    __shared__ int hist[256];
    __shared__ int cursor[256];
    __shared__ int cwsum[4], cwoff[4];
    unsigned expected = __hip_atomic_load(&g_bar_gen, __ATOMIC_RELAXED, __HIP_MEMORY_SCOPE_AGENT);
    const int b = blockIdx.x, t = threadIdx.x;
    const int lane = t & 63, wv = t >> 6;
    const int n = b * 1024 + t;
    if (t < 256) hist[t] = 0;
    int si = 0;
    if (n < NN) {
        int so = 0;
#pragma unroll
        for (int c = 0; c < CHUNKS; ++c) { so += g_pout[c * NN + n]; si += g_pin[c * NN + n]; }
        g_out_norm[n] = rsqrtf((float)max(so, 1));
        g_in_norm[n]  = rsqrtf((float)max(si, 1));
    }
    __syncthreads();
    int bin = min(si, 255);
    if (n < NN) atomicAdd(&hist[bin], 1);
    int inc = si;
#pragma unroll
    for (int off = 1; off < 64; off <<= 1) {
        int p = __shfl_up(inc, off, 64);
        if (lane >= off) inc += p;
    }
    if (lane == 63) wsum[wv] = inc;
    __syncthreads();
    if (t < 256) g_dhist[b * 256 + t] = hist[t];
    if (t < 16) {
        int x = wsum[t], y = x;
#pragma unroll
        for (int off = 1; off < 16; off <<= 1) {
            int p = __shfl_up(y, off, 16);
            if (t >= off) y += p;
        }
        woff[t] = y - x;
        if (t == 15) g_blocksum[b] = y;
    }
    gridbar(&expected);
    if (t < 64) {
        int own = (t < SCAN_B) ? g_blocksum[t] : 0;
        int v = own;
#pragma unroll
        for (int off = 1; off < 64; off <<= 1) {
            int p = __shfl_up(v, off, 64);
            if (t >= off) v += p;
        }
        bscan[t] = v - own;
        if (b == 0 && t == SCAN_B - 1) g_rowptr[NN] = v;  // total == NE
    }
    __syncthreads();
    int excl = (inc - si) + woff[wv] + bscan[b];
    if (n < NN) {
        g_rowptr[n] = excl;
        int run = excl;
#pragma unroll
        for (int c = 0; c < CHUNKS; ++c) {
            g_base[c * NN + n] = run;
            run += g_pin[c * NN + n];
        }
    }
    int cur = 0, tot = 0;
    if (t < 256) {
        for (int b2 = 0; b2 < SCAN_B; ++b2) {
            int h = g_dhist[b2 * 256 + t];
            cur += (b2 < b) ? h : 0;
            tot += h;
        }
    }
    int cinc = tot;
#pragma unroll
    for (int off = 1; off < 64; off <<= 1) {
        int p = __shfl_up(cinc, off, 64);
        if (lane >= off) cinc += p;
    }
    if (t < 256 && lane == 63) cwsum[wv] = cinc;
    __syncthreads();
    if (t < 4) {
        int x = cwsum[t], y = x;
#pragma unroll
        for (int off = 1; off < 4; off <<= 1) {
            int p = __shfl_up(y, off, 4);
            if (t >= off) y += p;
        }
        cwoff[t] = y - x;
    }
    __syncthreads();
    if (t < 256) cursor[t] = (cinc - tot) + cwoff[wv] + cur;
    __syncthreads();
    if (n < NN) {
        int pos = atomicAdd(&cursor[bin], 1);
        g_perm[pos] = n;
    }
}

// ---- K3: [place (blocks 0..239)] || [gemm0 tiles G1..GB) ----
__global__ __launch_bounds__(256) void k3_kernel(const int* __restrict__ src,
                                                 const int* __restrict__ dst,
                                                 const float* __restrict__ x,
                                                 const float* __restrict__ W0) {
    __shared__ __align__(16) int s_buf[8192];   // 32 KB; union of place cursors / gemm W
    const int tid = threadIdx.x;
    if (blockIdx.x < HB) {
        int* cur = s_buf;   // RSZ = 6250 ints = 25 KB
        int c = blockIdx.x / RANGES, r = blockIdx.x % RANGES;
        int lo = r * RSZ;
        for (int i = tid; i < RSZ; i += 256) cur[i] = g_base[c * NN + lo + i];
        __syncthreads();
        const int4* s4 = (const int4*)(src + c * CSZ);
        const int4* d4 = (const int4*)(dst + c * CSZ);
        for (int i = tid; i < CSZ / 4; i += 256) {
            int4 s = s4[i], d = d4[i];
            int v, p;
            v = d.x - lo; if ((unsigned)v < RSZ) { p = atomicAdd(&cur[v], 1); g_esrc[p] = s.x; }
            v = d.y - lo; if ((unsigned)v < RSZ) { p = atomicAdd(&cur[v], 1); g_esrc[p] = s.y; }
            v = d.z - lo; if ((unsigned)v < RSZ) { p = atomicAdd(&cur[v], 1); g_esrc[p] = s.z; }
            v = d.w - lo; if ((unsigned)v < RSZ) { p = atomicAdd(&cur[v], 1); g_esrc[p] = s.w; }
        }
    } else {
        gemm0_tile((_Float16*)s_buf, x, W0, blockIdx.x - HB + G1);
    }
}

// ---- MFMA GEMM (layers 1-2): C[M x N](fp16) = (A * out_norm[:,None]) @ W ----
template <int N>
__global__ __launch_bounds__(256) void gemm_mfma(int a_ib, int c_ib,
                                                 const float* __restrict__ Wg, int M) {
    constexpr int NT = N / 16;
    constexpr int LOGN = (N == 128) ? 7 : 6;
    __shared__ _Float16 Wl[128 * N];

    const int tid = threadIdx.x;
    for (int e = tid; e < 128 * N; e += 256) {
        int k = e >> LOGN, n = e & (N - 1);
        Wl[(((k >> 3) * N + n) << 3) + (k & 7)] = (_Float16)Wg[e];
    }
    __syncthreads();

    const int wv = tid >> 6, lane = tid & 63;
    const int quad = lane >> 4, mrow = lane & 15;
    const int rowbase = blockIdx.x * 64 + wv * 16;
    const int arow0 = rowbase + mrow;
    const int arow = (arow0 < M) ? arow0 : (M - 1);

    floatx4 acc[NT] = {};
    const __half* Ah = hbuf(a_ib);

#pragma unroll
    for (int kk = 0; kk < 4; ++kk) {
        const int k0 = kk * 32 + quad * 8;
        half8 afrag = *(const half8*)(Ah + (size_t)arow * 128 + k0);
#pragma unroll
        for (int nt = 0; nt < NT; ++nt) {
            half8 bfrag = *(const half8*)&Wl[(((kk * 4 + quad) * N + nt * 16 + mrow) << 3)];
            acc[nt] = __builtin_amdgcn_mfma_f32_16x16x32_f16(afrag, bfrag, acc[nt], 0, 0, 0);
        }
    }

    __half* C = hbuf(c_ib);
#pragma unroll
    for (int r = 0; r < 4; ++r) {
        int crow = rowbase + quad * 4 + r;
        if (crow < M) {
            float s = g_out_norm[crow];
#pragma unroll
            for (int nt = 0; nt < NT; ++nt) {
                float v = acc[nt][r] * s;
                C[(size_t)crow * N + nt * 16 + mrow] = __float2half_rn(v);
            }
        }
    }
}

__device__ __forceinline__ void acc_row(uint4 u, float wt,
                                        float& a0, float& a1, float& a2, float& a3,
                                        float& a4, float& a5, float& a6, float& a7) {
    float2 f0 = __half22float2(*(const __half2*)&u.x);
    float2 f1 = __half22float2(*(const __half2*)&u.y);
    float2 f2 = __half22float2(*(const __half2*)&u.z);
    float2 f3 = __half22float2(*(const __half2*)&u.w);
    a0 = fmaf(wt, f0.x, a0); a1 = fmaf(wt, f0.y, a1);
    a2 = fmaf(wt, f1.x, a2); a3 = fmaf(wt, f1.y, a3);
    a4 = fmaf(wt, f2.x, a4); a5 = fmaf(wt, f2.y, a5);
    a6 = fmaf(wt, f3.x, a6); a7 = fmaf(wt, f3.y, a7);
}

// Fused: gather(CSR, fp16 128-dim) -> [*out_norm[s] if SC] -> *in_norm + b -> relu -> LN -> fp16.
// Degree-sorted order; 4 nodes/wave, 16 lanes/node, uint4 per lane, unroll 8.
template <bool SC>
__global__ __launch_bounds__(256) void gather_ln_kernel(int s_ib, int d_ib,
                                                        const float* __restrict__ b,
                                                        const float* __restrict__ ln_s,
                                                        const float* __restrict__ ln_b) {
    int wave = threadIdx.x >> 6;
    int lane = threadIdx.x & 63;
    int sub = lane >> 4, sl = lane & 15;
    int idx = blockIdx.x * 16 + wave * 4 + sub;   // NN = 3125*16, always valid
    int node = g_perm[idx];
    const uint4* Hu = (const uint4*)hbuf(s_ib);
    int beg = g_rowptr[node], end = g_rowptr[node + 1];
    float a0 = 0.f, a1 = 0.f, a2 = 0.f, a3 = 0.f, a4 = 0.f, a5 = 0.f, a6 = 0.f, a7 = 0.f;
    int j = beg;
    for (; j + 7 < end; j += 8) {
        int ss[8]; uint4 uu[8]; float ww[8];
#pragma unroll
        for (int q = 0; q < 8; ++q) ss[q] = g_esrc[j + q];
#pragma unroll
        for (int q = 0; q < 8; ++q) uu[q] = Hu[ss[q] * 16 + sl];
#pragma unroll
        for (int q = 0; q < 8; ++q) ww[q] = SC ? g_out_norm[ss[q]] : 1.0f;
#pragma unroll
        for (int q = 0; q < 8; ++q) acc_row(uu[q], ww[q], a0, a1, a2, a3, a4, a5, a6, a7);
    }
    for (; j + 3 < end; j += 4) {
        int ss[4]; uint4 uu[4]; float ww[4];
#pragma unroll
        for (int q = 0; q < 4; ++q) ss[q] = g_esrc[j + q];
#pragma unroll
        for (int q = 0; q < 4; ++q) uu[q] = Hu[ss[q] * 16 + sl];
#pragma unroll
        for (int q = 0; q < 4; ++q) ww[q] = SC ? g_out_norm[ss[q]] : 1.0f;
#pragma unroll
        for (int q = 0; q < 4; ++q) acc_row(uu[q], ww[q], a0, a1, a2, a3, a4, a5, a6, a7);
    }
    for (; j < end; ++j) {
        int s0 = g_esrc[j];
        float w0 = SC ? g_out_norm[s0] : 1.0f;
        acc_row(Hu[s0 * 16 + sl], w0, a0, a1, a2, a3, a4, a5, a6, a7);
    }
    float nrm = g_in_norm[node];
    float4 bA = ((const float4*)b)[sl * 2], bB = ((const float4*)b)[sl * 2 + 1];
    float v0 = fmaxf(a0 * nrm + bA.x, 0.f), v1 = fmaxf(a1 * nrm + bA.y, 0.f);
    float v2 = fmaxf(a2 * nrm + bA.z, 0.f), v3 = fmaxf(a3 * nrm + bA.w, 0.f);
    float v4 = fmaxf(a4 * nrm + bB.x, 0.f), v5 = fmaxf(a5 * nrm + bB.y, 0.f);
    float v6 = fmaxf(a6 * nrm + bB.z, 0.f), v7 = fmaxf(a7 * nrm + bB.w, 0.f);
    float s = ((v0 + v1) + (v2 + v3)) + ((v4 + v5) + (v6 + v7));
    float sq = ((v0 * v0 + v1 * v1) + (v2 * v2 + v3 * v3)) +
               ((v4 * v4 + v5 * v5) + (v6 * v6 + v7 * v7));
#pragma unroll
    for (int off = 8; off > 0; off >>= 1) {
        s  += __shfl_xor(s, off, 64);
        sq += __shfl_xor(sq, off, 64);
    }
    float mean = s * (1.f / 128.f);
    float var = sq * (1.f / 128.f) - mean * mean;
    float inv = rsqrtf(var + LN_EPS);
    float4 lsA = ((const float4*)ln_s)[sl * 2], lsB = ((const float4*)ln_s)[sl * 2 + 1];
    float4 lbA = ((const float4*)ln_b)[sl * 2], lbB = ((const float4*)ln_b)[sl * 2 + 1];
    __half2 h0 = __floats2half2_rn((v0 - mean) * inv * lsA.x + lbA.x, (v1 - mean) * inv * lsA.y + lbA.y);
    __half2 h1 = __floats2half2_rn((v2 - mean) * inv * lsA.z + lbA.z, (v3 - mean) * inv * lsA.w + lbA.w);
    __half2 h2 = __floats2half2_rn((v4 - mean) * inv * lsB.x + lbB.x, (v5 - mean) * inv * lsB.y + lbB.y);
    __half2 h3 = __floats2half2_rn((v6 - mean) * inv * lsB.z + lbB.z, (v7 - mean) * inv * lsB.w + lbB.w);
    uint4 o = make_uint4(*(const unsigned int*)&h0, *(const unsigned int*)&h1,
                         *(const unsigned int*)&h2, *(const unsigned int*)&h3);
    ((uint4*)hbuf(d_ib))[node * 16 + sl] = o;
}

// Fused final: gather(CSR, fp16 64-dim) -> *in_norm + b2 -> relu -> fp32 out.
__global__ __launch_bounds__(256) void GCN_63831803953156_kernel(int s_ib,
                                                                 const float* __restrict__ b2,
                                                                 float* __restrict__ out) {
    int wave = threadIdx.x >> 6;
    int lane = threadIdx.x & 63;
    int sub = lane >> 3, sl = lane & 7;
    int idx = blockIdx.x * 32 + wave * 8 + sub;
    if (idx >= NN) return;
    int node = g_perm[idx];
    const uint4* Hu = (const uint4*)hbuf(s_ib);
    int beg = g_rowptr[node], end = g_rowptr[node + 1];
    float a0 = 0.f, a1 = 0.f, a2 = 0.f, a3 = 0.f, a4 = 0.f, a5 = 0.f, a6 = 0.f, a7 = 0.f;
    int j = beg;
    for (; j + 7 < end; j += 8) {
        int ss[8]; uint4 uu[8];
#pragma unroll
        for (int q = 0; q < 8; ++q) ss[q] = g_esrc[j + q];
#pragma unroll
        for (int q = 0; q < 8; ++q) uu[q] = Hu[ss[q] * 8 + sl];
#pragma unroll
        for (int q = 0; q < 8; ++q) acc_row(uu[q], 1.0f, a0, a1, a2, a3, a4, a5, a6, a7);
    }
    for (; j + 3 < end; j += 4) {
        int ss[4]; uint4 uu[4];
#pragma unroll
        for (int q = 0; q < 4; ++q) ss[q] = g_esrc[j + q];
#pragma unroll
        for (int q = 0; q < 4; ++q) uu[q] = Hu[ss[q] * 8 + sl];
#pragma unroll
        for (int q = 0; q < 4; ++q) acc_row(uu[q], 1.0f, a0, a1, a2, a3, a4, a5, a6, a7);
    }
    for (; j < end; ++j)
        acc_row(Hu[g_esrc[j] * 8 + sl], 1.0f, a0, a1, a2, a3, a4, a5, a6, a7);
    float nrm = g_in_norm[node];
    float4 bA = ((const float4*)b2)[sl * 2], bB = ((const float4*)b2)[sl * 2 + 1];
    float4 oA, oB;
    oA.x = fmaxf(a0 * nrm + bA.x, 0.f); oA.y = fmaxf(a1 * nrm + bA.y, 0.f);
    oA.z = fmaxf(a2 * nrm + bA.z, 0.f); oA.w = fmaxf(a3 * nrm + bA.w, 0.f);
    oB.x = fmaxf(a4 * nrm + bB.x, 0.f); oB.y = fmaxf(a5 * nrm + bB.y, 0.f);
    oB.z = fmaxf(a6 * nrm + bB.z, 0.f); oB.w = fmaxf(a7 * nrm + bB.w, 0.f);
    ((float4*)out)[node * 16 + sl * 2] = oA;
    ((float4*)out)[node * 16 + sl * 2 + 1] = oB;
}

extern "C" void kernel_launch(void* const* d_in, const int* in_sizes, int n_in,
                              void* d_out, int out_size, void* d_ws, size_t ws_size,
                              hipStream_t stream) {
    const float* x   = (const float*)d_in[0];
    const int* src   = (const int*)d_in[1];
    const int* dst   = (const int*)d_in[2];
    const float* W0  = (const float*)d_in[3];
    const float* b0  = (const float*)d_in[4];
    const float* W1  = (const float*)d_in[5];
    const float* b1  = (const float*)d_in[6];
    const float* W2  = (const float*)d_in[7];
    const float* b2  = (const float*)d_in[8];
    const float* ln_s = (const float*)d_in[9];
    const float* ln_b = (const float*)d_in[10];
    (void)d_ws; (void)ws_size; (void)in_sizes; (void)n_in; (void)out_size;

    // K1: histo || gemm0[0,G1) -> mid -> K3: place || gemm0[G1,GB)
    k1_kernel<<<HB + G1, 256, 0, stream>>>(src, dst, x, W0);
    mid_kernel<<<SCAN_B, 1024, 0, stream>>>();
    k3_kernel<<<HB + (GB - G1), 256, 0, stream>>>(src, dst, x, W0);

    // layer 0: fused gather (applies out_norm[s]) + LN: H0 -> H1
    gather_ln_kernel<true><<<NN / 16, 256, 0, stream>>>(0, 1, b0, ln_s, ln_b);

    // layer 1: gemm H1->H0 (epilogue-scaled), fused gather+LN H0->H1
    gemm_mfma<128><<<GB, 256, 0, stream>>>(1, 0, W1, NN);
    gather_ln_kernel<false><<<NN / 16, 256, 0, stream>>>(0, 1, b1, ln_s, ln_b);

    // layer 2 (128->64): gemm H1->H0, fused gather+relu H0->out
    gemm_mfma<64><<<GB, 256, 0, stream>>>(1, 0, W2, NN);
    GCN_63831803953156_kernel<<<(NN + 31) / 32, 256, 0, stream>>>(0, b2, (float*)d_out);
}

// Round 15
// 230.832 us; speedup vs baseline: 1.0083x; 1.0083x over previous
//
#include <hip/hip_runtime.h>
#include <hip/hip_fp16.h>

#define NN 50000
#define NE 600000
#define LN_EPS 1e-5f
#define SCAN_B 49    // 49 blocks x 1024 nodes covers 50176 >= NN
#define RANGES 8     // node ranges of 6250 (8*6250 = 50000)
#define RSZ 6250
#define CHUNKS 30    // edge chunks of 20000 (30*20000 = 600000); 240 histo blocks
#define CSZ 20000
#define HB (CHUNKS * RANGES)   // 240
#define GB ((NN + 63) / 64)    // 782 gemm tiles

typedef __attribute__((ext_vector_type(8))) _Float16 half8;
typedef __attribute__((ext_vector_type(4))) float floatx4;

// Module-level device scratch (graph-capture safe).
__device__ __align__(16) __half g_h0[NN * 128];
__device__ __align__(16) __half g_h1[NN * 128];
__device__ float g_out_norm[NN];
__device__ float g_in_norm[NN];
__device__ int g_rowptr[NN + 1];
__device__ int g_esrc[NE];
__device__ int g_blocksum[SCAN_B];
__device__ int g_perm[NN];             // degree-sorted node order (kills gather divergence)
__device__ int g_dhist[SCAN_B * 256];  // per-block degree histograms
// CSR-build privatized partials (no device-scope atomics in the hot path)
__device__ int g_pout[CHUNKS * NN];
__device__ int g_pin[CHUNKS * NN];
__device__ int g_base[CHUNKS * NN];
// grid-barrier state for mid_kernel's 49 co-resident blocks (generation-based)
__device__ unsigned g_bar_count = 0;
__device__ unsigned g_bar_gen = 0;

__device__ __forceinline__ __half* hbuf(int i) { return i ? g_h1 : g_h0; }

__device__ __forceinline__ void gridbar(unsigned* expected) {
    __syncthreads();
    if (threadIdx.x == 0) {
        __threadfence();
        unsigned prev = __hip_atomic_fetch_add(&g_bar_count, 1u, __ATOMIC_ACQ_REL,
                                               __HIP_MEMORY_SCOPE_AGENT);
        if (prev == gridDim.x - 1) {
            __hip_atomic_store(&g_bar_count, 0u, __ATOMIC_RELAXED, __HIP_MEMORY_SCOPE_AGENT);
            __hip_atomic_fetch_add(&g_bar_gen, 1u, __ATOMIC_RELEASE, __HIP_MEMORY_SCOPE_AGENT);
        } else {
            while (__hip_atomic_load(&g_bar_gen, __ATOMIC_ACQUIRE, __HIP_MEMORY_SCOPE_AGENT) ==
                   *expected)
                __builtin_amdgcn_s_sleep(8);
        }
        __threadfence();
    }
    __syncthreads();
    (*expected)++;
}

// ---- K1: fused [histo (blocks 0..239)] || [unscaled GEMM0 (blocks 240..1021)] ----
// Independent roles; GEMM0 omits out_norm scaling (folded into layer-0 gather by linearity).
__global__ __launch_bounds__(256) void k1_kernel(const int* __restrict__ src,
                                                 const int* __restrict__ dst,
                                                 const float* __restrict__ x,
                                                 const float* __restrict__ W0) {
    __shared__ __align__(16) int s_buf[2 * RSZ];   // 50 KB; union of histo/gemm LDS
    const int tid = threadIdx.x;
    if (blockIdx.x < HB) {
        // ---- histo role ----
        int* h_out = s_buf;
        int* h_in = s_buf + RSZ;
        int c = blockIdx.x / RANGES, r = blockIdx.x % RANGES;
        int lo = r * RSZ;
        for (int i = tid; i < RSZ; i += 256) { h_out[i] = 0; h_in[i] = 0; }
        __syncthreads();
        const int4* s4 = (const int4*)(src + c * CSZ);
        const int4* d4 = (const int4*)(dst + c * CSZ);
        for (int i = tid; i < CSZ / 4; i += 256) {
            int4 s = s4[i], d = d4[i];
            int v;
            v = s.x - lo; if ((unsigned)v < RSZ) atomicAdd(&h_out[v], 1);
            v = s.y - lo; if ((unsigned)v < RSZ) atomicAdd(&h_out[v], 1);
            v = s.z - lo; if ((unsigned)v < RSZ) atomicAdd(&h_out[v], 1);
            v = s.w - lo; if ((unsigned)v < RSZ) atomicAdd(&h_out[v], 1);
            v = d.x - lo; if ((unsigned)v < RSZ) atomicAdd(&h_in[v], 1);
            v = d.y - lo; if ((unsigned)v < RSZ) atomicAdd(&h_in[v], 1);
            v = d.z - lo; if ((unsigned)v < RSZ) atomicAdd(&h_in[v], 1);
            v = d.w - lo; if ((unsigned)v < RSZ) atomicAdd(&h_in[v], 1);
        }
        __syncthreads();
        for (int i = tid; i < RSZ; i += 256) {
            g_pout[c * NN + lo + i] = h_out[i];
            g_pin[c * NN + lo + i]  = h_in[i];
        }
    } else {
        // ---- gemm0 role: H0 = fp16(x @ W0), no scaling ----
        _Float16* Wl = (_Float16*)s_buf;   // 32 KB swizzled
        for (int e = tid; e < 128 * 128; e += 256) {
            int k = e >> 7, n = e & 127;
            Wl[(((k >> 3) * 128 + n) << 3) + (k & 7)] = (_Float16)W0[e];
        }
        __syncthreads();
        const int gb = blockIdx.x - HB;
        const int wv = tid >> 6, lane = tid & 63;
        const int quad = lane >> 4, mrow = lane & 15;
        const int rowbase = gb * 64 + wv * 16;
        const int arow0 = rowbase + mrow;
        const int arow = (arow0 < NN) ? arow0 : (NN - 1);
        floatx4 acc[8] = {};
#pragma unroll
        for (int kk = 0; kk < 4; ++kk) {
            const int k0 = kk * 32 + quad * 8;
            const float4* ap = (const float4*)(x + (size_t)arow * 128 + k0);
            float4 f0 = ap[0], f1 = ap[1];
            half8 afrag;
            afrag[0] = (_Float16)f0.x; afrag[1] = (_Float16)f0.y;
            afrag[2] = (_Float16)f0.z; afrag[3] = (_Float16)f0.w;
            afrag[4] = (_Float16)f1.x; afrag[5] = (_Float16)f1.y;
            afrag[6] = (_Float16)f1.z; afrag[7] = (_Float16)f1.w;
#pragma unroll
            for (int nt = 0; nt < 8; ++nt) {
                half8 bfrag = *(const half8*)&Wl[(((kk * 4 + quad) * 128 + nt * 16 + mrow) << 3)];
                acc[nt] = __builtin_amdgcn_mfma_f32_16x16x32_f16(afrag, bfrag, acc[nt], 0, 0, 0);
            }
        }
        __half* C = hbuf(0);
#pragma unroll
        for (int r = 0; r < 4; ++r) {
            int crow = rowbase + quad * 4 + r;
            if (crow < NN) {
#pragma unroll
                for (int nt = 0; nt < 8; ++nt)
                    C[(size_t)crow * 128 + nt * 16 + mrow] = __float2half_rn(acc[nt][r]);
            }
        }
    }
}

// ---- Fused mid: degrees/norms + exclusive scan (shuffle-based) + cursor bases + degree-sort.
// 49 blocks x 1024 threads, one internal grid barrier. ----
__global__ __launch_bounds__(1024) void mid_kernel() {
    __shared__ int wsum[16], woff[16];
    __shared__ int bscan[64];
    __shared__ int hist[256];
    __shared__ int cursor[256];
    __shared__ int cwsum[4], cwoff[4];
    unsigned expected = __hip_atomic_load(&g_bar_gen, __ATOMIC_RELAXED, __HIP_MEMORY_SCOPE_AGENT);
    const int b = blockIdx.x, t = threadIdx.x;
    const int lane = t & 63, wv = t >> 6;
    const int n = b * 1024 + t;
    if (t < 256) hist[t] = 0;
    int si = 0;
    if (n < NN) {
        int so = 0;
#pragma unroll
        for (int c = 0; c < CHUNKS; ++c) { so += g_pout[c * NN + n]; si += g_pin[c * NN + n]; }
        g_out_norm[n] = rsqrtf((float)max(so, 1));
        g_in_norm[n]  = rsqrtf((float)max(si, 1));
    }
    __syncthreads();  // hist init visible
    int bin = min(si, 255);
    if (n < NN) atomicAdd(&hist[bin], 1);
    // wave-inclusive scan of si (shuffle)
    int inc = si;
#pragma unroll
    for (int off = 1; off < 64; off <<= 1) {
        int p = __shfl_up(inc, off, 64);
        if (lane >= off) inc += p;
    }
    if (lane == 63) wsum[wv] = inc;
    __syncthreads();  // wsum + hist atomics complete
    if (t < 256) g_dhist[b * 256 + t] = hist[t];
    if (t < 16) {
        int x = wsum[t], y = x;
#pragma unroll
        for (int off = 1; off < 16; off <<= 1) {
            int p = __shfl_up(y, off, 16);
            if (t >= off) y += p;
        }
        woff[t] = y - x;
        if (t == 15) g_blocksum[b] = y;
    }
    gridbar(&expected);
    if (t < 64) {
        int own = (t < SCAN_B) ? g_blocksum[t] : 0;
        int v = own;
#pragma unroll
        for (int off = 1; off < 64; off <<= 1) {
            int p = __shfl_up(v, off, 64);
            if (t >= off) v += p;
        }
        bscan[t] = v - own;
        if (b == 0 && t == SCAN_B - 1) g_rowptr[NN] = v;  // total == NE
    }
    __syncthreads();
    int excl = (inc - si) + woff[wv] + bscan[b];
    if (n < NN) {
        g_rowptr[n] = excl;
        int run = excl;
#pragma unroll
        for (int c = 0; c < CHUNKS; ++c) {
            g_base[c * NN + n] = run;
            run += g_pin[c * NN + n];
        }
    }
    // ---- degree-sorted permutation ----
    int cur = 0, tot = 0;
    if (t < 256) {
        for (int b2 = 0; b2 < SCAN_B; ++b2) {
            int h = g_dhist[b2 * 256 + t];
            cur += (b2 < b) ? h : 0;
            tot += h;
        }
    }
    int cinc = tot;
#pragma unroll
    for (int off = 1; off < 64; off <<= 1) {
        int p = __shfl_up(cinc, off, 64);
        if (lane >= off) cinc += p;
    }
    if (t < 256 && lane == 63) cwsum[wv] = cinc;
    __syncthreads();
    if (t < 4) {
        int x = cwsum[t], y = x;
#pragma unroll
        for (int off = 1; off < 4; off <<= 1) {
            int p = __shfl_up(y, off, 4);
            if (t >= off) y += p;
        }
        cwoff[t] = y - x;
    }
    __syncthreads();
    if (t < 256) cursor[t] = (cinc - tot) + cwoff[wv] + cur;  // global start of (block b, bin t)
    __syncthreads();
    if (n < NN) {
        int pos = atomicAdd(&cursor[bin], 1);
        g_perm[pos] = n;
    }
}

// ---- Pass C: CSR placement via LDS cursors (no device-scope atomics) ----
__global__ __launch_bounds__(256) void place_lds_kernel(const int* __restrict__ src,
                                                        const int* __restrict__ dst) {
    __shared__ int cur[RSZ];
    int c = blockIdx.x / RANGES, r = blockIdx.x % RANGES;
    int lo = r * RSZ;
    for (int i = threadIdx.x; i < RSZ; i += 256) cur[i] = g_base[c * NN + lo + i];
    __syncthreads();
    const int4* s4 = (const int4*)(src + c * CSZ);
    const int4* d4 = (const int4*)(dst + c * CSZ);
    for (int i = threadIdx.x; i < CSZ / 4; i += 256) {
        int4 s = s4[i], d = d4[i];
        int v, p;
        v = d.x - lo; if ((unsigned)v < RSZ) { p = atomicAdd(&cur[v], 1); g_esrc[p] = s.x; }
        v = d.y - lo; if ((unsigned)v < RSZ) { p = atomicAdd(&cur[v], 1); g_esrc[p] = s.y; }
        v = d.z - lo; if ((unsigned)v < RSZ) { p = atomicAdd(&cur[v], 1); g_esrc[p] = s.z; }
        v = d.w - lo; if ((unsigned)v < RSZ) { p = atomicAdd(&cur[v], 1); g_esrc[p] = s.w; }
    }
}

// ---- MFMA GEMM (layers 1-2): C[M x N](fp16) = (A * out_norm[:,None]) @ W ----
template <int N>
__global__ __launch_bounds__(256) void gemm_mfma(int a_ib, int c_ib,
                                                 const float* __restrict__ Wg, int M) {
    constexpr int NT = N / 16;
    constexpr int LOGN = (N == 128) ? 7 : 6;
    __shared__ _Float16 Wl[128 * N];

    const int tid = threadIdx.x;
    for (int e = tid; e < 128 * N; e += 256) {
        int k = e >> LOGN, n = e & (N - 1);
        Wl[(((k >> 3) * N + n) << 3) + (k & 7)] = (_Float16)Wg[e];
    }
    __syncthreads();

    const int wv = tid >> 6, lane = tid & 63;
    const int quad = lane >> 4, mrow = lane & 15;
    const int rowbase = blockIdx.x * 64 + wv * 16;
    const int arow0 = rowbase + mrow;
    const int arow = (arow0 < M) ? arow0 : (M - 1);

    floatx4 acc[NT] = {};
    const __half* Ah = hbuf(a_ib);

#pragma unroll
    for (int kk = 0; kk < 4; ++kk) {
        const int k0 = kk * 32 + quad * 8;
        half8 afrag = *(const half8*)(Ah + (size_t)arow * 128 + k0);
#pragma unroll
        for (int nt = 0; nt < NT; ++nt) {
            half8 bfrag = *(const half8*)&Wl[(((kk * 4 + quad) * N + nt * 16 + mrow) << 3)];
            acc[nt] = __builtin_amdgcn_mfma_f32_16x16x32_f16(afrag, bfrag, acc[nt], 0, 0, 0);
        }
    }

    __half* C = hbuf(c_ib);
#pragma unroll
    for (int r = 0; r < 4; ++r) {
        int crow = rowbase + quad * 4 + r;
        if (crow < M) {
            float s = g_out_norm[crow];
#pragma unroll
            for (int nt = 0; nt < NT; ++nt) {
                float v = acc[nt][r] * s;
                C[(size_t)crow * N + nt * 16 + mrow] = __float2half_rn(v);
            }
        }
    }
}

__device__ __forceinline__ void acc_row(uint4 u, float wt,
                                        float& a0, float& a1, float& a2, float& a3,
                                        float& a4, float& a5, float& a6, float& a7) {
    float2 f0 = __half22float2(*(const __half2*)&u.x);
    float2 f1 = __half22float2(*(const __half2*)&u.y);
    float2 f2 = __half22float2(*(const __half2*)&u.z);
    float2 f3 = __half22float2(*(const __half2*)&u.w);
    a0 = fmaf(wt, f0.x, a0); a1 = fmaf(wt, f0.y, a1);
    a2 = fmaf(wt, f1.x, a2); a3 = fmaf(wt, f1.y, a3);
    a4 = fmaf(wt, f2.x, a4); a5 = fmaf(wt, f2.y, a5);
    a6 = fmaf(wt, f3.x, a6); a7 = fmaf(wt, f3.y, a7);
}

// Fused: gather(CSR, fp16 128-dim) -> [*out_norm[s] if SC] -> *in_norm + b -> relu -> LN -> fp16.
// Degree-sorted order; 4 nodes/wave, 16 lanes/node, uint4 per lane, unroll 8.
template <bool SC>
__global__ __launch_bounds__(256) void gather_ln_kernel(int s_ib, int d_ib,
                                                        const float* __restrict__ b,
                                                        const float* __restrict__ ln_s,
                                                        const float* __restrict__ ln_b) {
    int wave = threadIdx.x >> 6;
    int lane = threadIdx.x & 63;
    int sub = lane >> 4, sl = lane & 15;
    int idx = blockIdx.x * 16 + wave * 4 + sub;   // NN = 3125*16, always valid
    int node = g_perm[idx];
    const uint4* Hu = (const uint4*)hbuf(s_ib);   // 16 uint4 per 128-dim row
    int beg = g_rowptr[node], end = g_rowptr[node + 1];
    float a0 = 0.f, a1 = 0.f, a2 = 0.f, a3 = 0.f, a4 = 0.f, a5 = 0.f, a6 = 0.f, a7 = 0.f;
    int j = beg;
    for (; j + 7 < end; j += 8) {
        int ss[8]; uint4 uu[8]; float ww[8];
#pragma unroll
        for (int q = 0; q < 8; ++q) ss[q] = g_esrc[j + q];
#pragma unroll
        for (int q = 0; q < 8; ++q) uu[q] = Hu[ss[q] * 16 + sl];
#pragma unroll
        for (int q = 0; q < 8; ++q) ww[q] = SC ? g_out_norm[ss[q]] : 1.0f;
#pragma unroll
        for (int q = 0; q < 8; ++q) acc_row(uu[q], ww[q], a0, a1, a2, a3, a4, a5, a6, a7);
    }
    for (; j + 3 < end; j += 4) {
        int ss[4]; uint4 uu[4]; float ww[4];
#pragma unroll
        for (int q = 0; q < 4; ++q) ss[q] = g_esrc[j + q];
#pragma unroll
        for (int q = 0; q < 4; ++q) uu[q] = Hu[ss[q] * 16 + sl];
#pragma unroll
        for (int q = 0; q < 4; ++q) ww[q] = SC ? g_out_norm[ss[q]] : 1.0f;
#pragma unroll
        for (int q = 0; q < 4; ++q) acc_row(uu[q], ww[q], a0, a1, a2, a3, a4, a5, a6, a7);
    }
    for (; j < end; ++j) {
        int s0 = g_esrc[j];
        float w0 = SC ? g_out_norm[s0] : 1.0f;
        acc_row(Hu[s0 * 16 + sl], w0, a0, a1, a2, a3, a4, a5, a6, a7);
    }
    float nrm = g_in_norm[node];
    float4 bA = ((const float4*)b)[sl * 2], bB = ((const float4*)b)[sl * 2 + 1];
    float v0 = fmaxf(a0 * nrm + bA.x, 0.f), v1 = fmaxf(a1 * nrm + bA.y, 0.f);
    float v2 = fmaxf(a2 * nrm + bA.z, 0.f), v3 = fmaxf(a3 * nrm + bA.w, 0.f);
    float v4 = fmaxf(a4 * nrm + bB.x, 0.f), v5 = fmaxf(a5 * nrm + bB.y, 0.f);
    float v6 = fmaxf(a6 * nrm + bB.z, 0.f), v7 = fmaxf(a7 * nrm + bB.w, 0.f);
    float s = ((v0 + v1) + (v2 + v3)) + ((v4 + v5) + (v6 + v7));
    float sq = ((v0 * v0 + v1 * v1) + (v2 * v2 + v3 * v3)) +
               ((v4 * v4 + v5 * v5) + (v6 * v6 + v7 * v7));
#pragma unroll
    for (int off = 8; off > 0; off >>= 1) {
        s  += __shfl_xor(s, off, 64);
        sq += __shfl_xor(sq, off, 64);
    }
    float mean = s * (1.f / 128.f);
    float var = sq * (1.f / 128.f) - mean * mean;
    float inv = rsqrtf(var + LN_EPS);
    float4 lsA = ((const float4*)ln_s)[sl * 2], lsB = ((const float4*)ln_s)[sl * 2 + 1];
    float4 lbA = ((const float4*)ln_b)[sl * 2], lbB = ((const float4*)ln_b)[sl * 2 + 1];
    __half2 h0 = __floats2half2_rn((v0 - mean) * inv * lsA.x + lbA.x, (v1 - mean) * inv * lsA.y + lbA.y);
    __half2 h1 = __floats2half2_rn((v2 - mean) * inv * lsA.z + lbA.z, (v3 - mean) * inv * lsA.w + lbA.w);
    __half2 h2 = __floats2half2_rn((v4 - mean) * inv * lsB.x + lbB.x, (v5 - mean) * inv * lsB.y + lbB.y);
    __half2 h3 = __floats2half2_rn((v6 - mean) * inv * lsB.z + lbB.z, (v7 - mean) * inv * lsB.w + lbB.w);
    uint4 o = make_uint4(*(const unsigned int*)&h0, *(const unsigned int*)&h1,
                         *(const unsigned int*)&h2, *(const unsigned int*)&h3);
    ((uint4*)hbuf(d_ib))[node * 16 + sl] = o;
}

// Fused final: gather(CSR, fp16 64-dim) -> *in_norm + b2 -> relu -> fp32 out.
// Degree-sorted order; 8 nodes/wave, 8 lanes/node, uint4 loads, unroll 8.
__global__ __launch_bounds__(256) void GCN_63831803953156_kernel(int s_ib,
                                                                 const float* __restrict__ b2,
                                                                 float* __restrict__ out) {
    int wave = threadIdx.x >> 6;
    int lane = threadIdx.x & 63;
    int sub = lane >> 3, sl = lane & 7;
    int idx = blockIdx.x * 32 + wave * 8 + sub;
    if (idx >= NN) return;
    int node = g_perm[idx];
    const uint4* Hu = (const uint4*)hbuf(s_ib);   // 8 uint4 per 64-dim row
    int beg = g_rowptr[node], end = g_rowptr[node + 1];
    float a0 = 0.f, a1 = 0.f, a2 = 0.f, a3 = 0.f, a4 = 0.f, a5 = 0.f, a6 = 0.f, a7 = 0.f;
    int j = beg;
    for (; j + 7 < end; j += 8) {
        int ss[8]; uint4 uu[8];
#pragma unroll
        for (int q = 0; q < 8; ++q) ss[q] = g_esrc[j + q];
#pragma unroll
        for (int q = 0; q < 8; ++q) uu[q] = Hu[ss[q] * 8 + sl];
#pragma unroll
        for (int q = 0; q < 8; ++q) acc_row(uu[q], 1.0f, a0, a1, a2, a3, a4, a5, a6, a7);
    }
    for (; j + 3 < end; j += 4) {
        int ss[4]; uint4 uu[4];
#pragma unroll
        for (int q = 0; q < 4; ++q) ss[q] = g_esrc[j + q];
#pragma unroll
        for (int q = 0; q < 4; ++q) uu[q] = Hu[ss[q] * 8 + sl];
#pragma unroll
        for (int q = 0; q < 4; ++q) acc_row(uu[q], 1.0f, a0, a1, a2, a3, a4, a5, a6, a7);
    }
    for (; j < end; ++j)
        acc_row(Hu[g_esrc[j] * 8 + sl], 1.0f, a0, a1, a2, a3, a4, a5, a6, a7);
    float nrm = g_in_norm[node];
    float4 bA = ((const float4*)b2)[sl * 2], bB = ((const float4*)b2)[sl * 2 + 1];
    float4 oA, oB;
    oA.x = fmaxf(a0 * nrm + bA.x, 0.f); oA.y = fmaxf(a1 * nrm + bA.y, 0.f);
    oA.z = fmaxf(a2 * nrm + bA.z, 0.f); oA.w = fmaxf(a3 * nrm + bA.w, 0.f);
    oB.x = fmaxf(a4 * nrm + bB.x, 0.f); oB.y = fmaxf(a5 * nrm + bB.y, 0.f);
    oB.z = fmaxf(a6 * nrm + bB.z, 0.f); oB.w = fmaxf(a7 * nrm + bB.w, 0.f);
    ((float4*)out)[node * 16 + sl * 2] = oA;
    ((float4*)out)[node * 16 + sl * 2 + 1] = oB;
}

extern "C" void kernel_launch(void* const* d_in, const int* in_sizes, int n_in,
                              void* d_out, int out_size, void* d_ws, size_t ws_size,
                              hipStream_t stream) {
    const float* x   = (const float*)d_in[0];
    const int* src   = (const int*)d_in[1];
    const int* dst   = (const int*)d_in[2];
    const float* W0  = (const float*)d_in[3];
    const float* b0  = (const float*)d_in[4];
    const float* W1  = (const float*)d_in[5];
    const float* b1  = (const float*)d_in[6];
    const float* W2  = (const float*)d_in[7];
    const float* b2  = (const float*)d_in[8];
    const float* ln_s = (const float*)d_in[9];
    const float* ln_b = (const float*)d_in[10];
    (void)d_ws; (void)ws_size; (void)in_sizes; (void)n_in; (void)out_size;

    // K1: histo || unscaled GEMM0 (independent) -> mid -> place
    k1_kernel<<<HB + GB, 256, 0, stream>>>(src, dst, x, W0);
    mid_kernel<<<SCAN_B, 1024, 0, stream>>>();
    place_lds_kernel<<<HB, 256, 0, stream>>>(src, dst);

    // layer 0: fused gather (applies out_norm[s]) + LN: H0 -> H1
    gather_ln_kernel<true><<<NN / 16, 256, 0, stream>>>(0, 1, b0, ln_s, ln_b);

    // layer 1: gemm H1->H0 (epilogue-scaled), fused gather+LN H0->H1
    gemm_mfma<128><<<GB, 256, 0, stream>>>(1, 0, W1, NN);
    gather_ln_kernel<false><<<NN / 16, 256, 0, stream>>>(0, 1, b1, ln_s, ln_b);

    // layer 2 (128->64): gemm H1->H0, fused gather+relu H0->out
    gemm_mfma<64><<<GB, 256, 0, stream>>>(1, 0, W2, NN);
    GCN_63831803953156_kernel<<<(NN + 31) / 32, 256, 0, stream>>>(0, b2, (float*)d_out);
}